// Round 8
// baseline (291.629 us; speedup 1.0000x reference)
//
#include <hip/hip_runtime.h>
#include <hip/hip_bf16.h>

#define IN_CH 128
#define D1 256      // HEADS*HID
#define HID 64
#define HEADS 4
#define SCAN_BLK 1024

typedef _Float16 h16;
typedef __attribute__((ext_vector_type(4))) _Float16 half4v;
typedef __attribute__((ext_vector_type(8))) _Float16 half8v;
typedef __attribute__((ext_vector_type(4))) float f32x4;

__device__ __forceinline__ float lrelu02(float v) { return v > 0.f ? v : 0.2f * v; }
__device__ __forceinline__ float lrelu001(float v) { return v > 0.f ? v : 0.01f * v; }

// ---- setup: prep weights (blocks 0..3) | cast x->fp16 (castBlocks) | hist (rest) ----
__global__ __launch_bounds__(256) void setup_kernel(const float* __restrict__ x,
                                                    const float* __restrict__ W1,
                                                    const float* __restrict__ W2,
                                                    const float* __restrict__ a_src1,
                                                    const float* __restrict__ a_dst1,
                                                    const float* __restrict__ a_src2,
                                                    const float* __restrict__ a_dst2,
                                                    const int* __restrict__ ei,
                                                    int* __restrict__ cnt,
                                                    h16* __restrict__ xh,
                                                    h16* __restrict__ w1t,
                                                    h16* __restrict__ w2t,
                                                    long xtotal, long xvalid,
                                                    int nE, int castBlocks) {
    const int b = blockIdx.x;
    const int t = threadIdx.x;
    if (b == 0) {
        for (int k = 0; k < IN_CH; ++k) w1t[t * IN_CH + k] = (h16)W1[k * D1 + t];
    } else if (b == 1) {
        if (t < HID)
            for (int k = 0; k < D1; ++k) w2t[t * D1 + k] = (h16)W2[k * HID + t];
        for (int i = t; i < 14 * D1; i += 256) w2t[66 * D1 + i] = (h16)0.f;
    } else if (b == 2) {
        for (int o = t; o < 1024; o += 256) {
            int v = o >> 7, k = o & 127;
            int h = v & 3;
            const float* avec = (v >> 2) ? (a_dst1 + h * HID) : (a_src1 + h * HID);
            const float* wrow = W1 + k * D1 + h * HID;
            float s = 0.f;
            for (int c = 0; c < HID; ++c) s += wrow[c] * avec[c];
            w1t[(256 + v) * IN_CH + k] = (h16)s;
            w1t[(264 + v) * IN_CH + k] = (h16)0.f;
        }
    } else if (b == 3) {
        for (int o = t; o < 512; o += 256) {
            int v = o >> 8, k = o & 255;
            const float* avec = v ? a_dst2 : a_src2;
            const float* wrow = W2 + k * HID;
            float s = 0.f;
            for (int c = 0; c < HID; ++c) s += wrow[c] * avec[c];
            w2t[(64 + v) * D1 + k] = (h16)s;
        }
    } else if (b < 4 + castBlocks) {
        long i = ((long)(b - 4) * 256 + t) * 4;
        if (i < xtotal) {
            float4 v = make_float4(0.f, 0.f, 0.f, 0.f);
            if (i < xvalid) v = *(const float4*)&x[i];
            half4v o; o.x = (h16)v.x; o.y = (h16)v.y; o.z = (h16)v.z; o.w = (h16)v.w;
            *(half4v*)&xh[i] = o;
        }
    } else {
        int e = (b - 4 - castBlocks) * 256 + t;
        if (e < nE) atomicAdd(&cnt[ei[nE + e]], 1);
    }
}

// ---- scan1: per-block exclusive scan (1024 elems), block totals out ----
__global__ __launch_bounds__(256) void scan1_kernel(const int* __restrict__ cnt,
                                                    int* __restrict__ pre,
                                                    int* __restrict__ blockSums, int n) {
    __shared__ int lds[256];
    const int t = threadIdx.x;
    const int base = blockIdx.x * SCAN_BLK + t * 4;
    int v0 = 0, v1 = 0, v2 = 0, v3 = 0;
    if (base + 0 < n) v0 = cnt[base + 0];
    if (base + 1 < n) v1 = cnt[base + 1];
    if (base + 2 < n) v2 = cnt[base + 2];
    if (base + 3 < n) v3 = cnt[base + 3];
    int s = v0 + v1 + v2 + v3;
    lds[t] = s;
    __syncthreads();
    for (int off = 1; off < 256; off <<= 1) {
        int x = 0;
        if (t >= off) x = lds[t - off];
        __syncthreads();
        if (t >= off) lds[t] += x;
        __syncthreads();
    }
    int excl = lds[t] - s;
    if (t == 255) blockSums[blockIdx.x] = lds[255];
    if (base + 0 < n) pre[base + 0] = excl;
    if (base + 1 < n) pre[base + 1] = excl + v0;
    if (base + 2 < n) pre[base + 2] = excl + v0 + v1;
    if (base + 3 < n) pre[base + 3] = excl + v0 + v1 + v2;
}

// ---- scan23: add block offsets (wave-parallel partial sum of blockSums) ----
__global__ __launch_bounds__(256) void scan23_kernel(int* __restrict__ pre,
                                                     const int* __restrict__ blockSums,
                                                     int* __restrict__ cursor,
                                                     int n, int nE, int nb) {
    __shared__ int soff_s;
    const int t = threadIdx.x;
    if (t < 64) {
        int v = (t < blockIdx.x && t < nb) ? blockSums[t] : 0;   // nb <= 64
        #pragma unroll
        for (int off = 1; off < 64; off <<= 1) v += __shfl_xor(v, off, 64);
        if (t == 0) soff_s = v;
    }
    __syncthreads();
    const int soff = soff_s;
    const int base = blockIdx.x * SCAN_BLK + t * 4;
    #pragma unroll
    for (int q = 0; q < 4; ++q) {
        int i = base + q;
        if (i < n) {
            int v = pre[i] + soff;
            pre[i] = v;
            cursor[i] = v;
        }
    }
    if (blockIdx.x == 0 && t == 0) pre[n] = nE;
}

__global__ __launch_bounds__(256) void scatter_kernel(const int* __restrict__ ei,
                                                      int* __restrict__ cursor,
                                                      int2* __restrict__ sd, int nE) {
    int e = blockIdx.x * 256 + threadIdx.x;
    if (e >= nE) return;
    int src = ei[e];
    int dst = ei[nE + e];
    int pos = atomicAdd(&cursor[dst], 1);
    sd[pos] = make_int2(src, dst);
}

// ---- MFMA GEMM1: h1[N,256](fp16) + asad[N,8] = xh[NP,128] @ w1t ----
__global__ __launch_bounds__(256) void gemm1_mfma(const h16* __restrict__ xh,
                                                  const h16* __restrict__ w1t,
                                                  h16* __restrict__ h1,
                                                  float* __restrict__ asad, int n) {
    const int wave = threadIdx.x >> 6, lane = threadIdx.x & 63;
    const int r = lane & 15, ksel = lane >> 4;
    const int rowBase = blockIdx.x * 64 + wave * 16;
    const h16* xrow = xh + (size_t)(rowBase + r) * IN_CH + ksel * 8;
    half8v a[4];
    #pragma unroll
    for (int kk = 0; kk < 4; ++kk) a[kk] = *(const half8v*)(xrow + kk * 32);
    f32x4 acc[17];
    #pragma unroll
    for (int ct = 0; ct < 17; ++ct) acc[ct] = (f32x4){0.f, 0.f, 0.f, 0.f};
    #pragma unroll
    for (int ct = 0; ct < 17; ++ct) {
        const h16* wrow = w1t + (size_t)(ct * 16 + r) * IN_CH + ksel * 8;
        #pragma unroll
        for (int kk = 0; kk < 4; ++kk) {
            half8v b = *(const half8v*)(wrow + kk * 32);
            acc[ct] = __builtin_amdgcn_mfma_f32_16x16x32_f16(a[kk], b, acc[ct], 0, 0, 0);
        }
    }
    #pragma unroll
    for (int i = 0; i < 4; ++i) {
        int row = rowBase + ksel * 4 + i;
        if (row < n) {
            #pragma unroll
            for (int ct = 0; ct < 16; ++ct)
                h1[(size_t)row * D1 + ct * 16 + r] = (h16)acc[ct][i];
            if (r < 8) asad[(size_t)row * 8 + r] = acc[16][i];
        }
    }
}

// ---- MFMA GEMM2: h2[N,64](fp16) + asad2[N,2] = hmid[NP,256] @ w2t ----
__global__ __launch_bounds__(256) void gemm2_mfma(const h16* __restrict__ hm,
                                                  const h16* __restrict__ w2t,
                                                  h16* __restrict__ h2,
                                                  float* __restrict__ asad2, int n) {
    const int wave = threadIdx.x >> 6, lane = threadIdx.x & 63;
    const int r = lane & 15, ksel = lane >> 4;
    const int rowBase = blockIdx.x * 64 + wave * 16;
    const h16* xrow = hm + (size_t)(rowBase + r) * D1 + ksel * 8;
    half8v a[8];
    #pragma unroll
    for (int kk = 0; kk < 8; ++kk) a[kk] = *(const half8v*)(xrow + kk * 32);
    f32x4 acc[5];
    #pragma unroll
    for (int ct = 0; ct < 5; ++ct) acc[ct] = (f32x4){0.f, 0.f, 0.f, 0.f};
    #pragma unroll
    for (int ct = 0; ct < 5; ++ct) {
        const h16* wrow = w2t + (size_t)(ct * 16 + r) * D1 + ksel * 8;
        #pragma unroll
        for (int kk = 0; kk < 8; ++kk) {
            half8v b = *(const half8v*)(wrow + kk * 32);
            acc[ct] = __builtin_amdgcn_mfma_f32_16x16x32_f16(a[kk], b, acc[ct], 0, 0, 0);
        }
    }
    #pragma unroll
    for (int i = 0; i < 4; ++i) {
        int row = rowBase + ksel * 4 + i;
        if (row < n) {
            #pragma unroll
            for (int ct = 0; ct < 4; ++ct)
                h2[(size_t)row * HID + ct * 16 + r] = (h16)acc[ct][i];
            if (r < 2) asad2[(size_t)row * 2 + r] = acc[4][i];
        }
    }
}

// ---- edge weights layer1 (CSR order), fp16 ----
__global__ __launch_bounds__(256) void ewt1_kernel(const int2* __restrict__ sd,
                                                   const float* __restrict__ asad,
                                                   h16* __restrict__ wE1, int nE4) {
    int t = blockIdx.x * 256 + threadIdx.x;
    if (t >= nE4) return;
    int j = t >> 2, h = t & 3;
    int2 p = sd[j];
    wE1[t] = (h16)expf(lrelu02(asad[(size_t)p.x * 8 + h] + asad[(size_t)p.y * 8 + 4 + h]));
}

// ---- gather1: wave per dst node; 2 edges in parallel (32 lanes x 16B each);
//      fused bias+LN+lrelu; fp16 out ----
__global__ __launch_bounds__(256) void gather1_kernel(const h16* __restrict__ h1,
                                                      const float* __restrict__ asad,
                                                      const h16* __restrict__ wE1,
                                                      const int* __restrict__ rowStart,
                                                      const int2* __restrict__ sd,
                                                      const float* __restrict__ b1,
                                                      const float* __restrict__ gamma,
                                                      const float* __restrict__ beta,
                                                      h16* __restrict__ hmid, int n, int npad) {
    const int lane = threadIdx.x & 63;
    const int node = (blockIdx.x * 256 + threadIdx.x) >> 6;
    if (node >= npad) return;
    const int li = lane & 31;          // channel group: channels li*8 .. li*8+7
    const int eh = lane >> 5;          // which edge of the pair
    const int head = li >> 3;
    if (node >= n) {                   // zero pad rows (gemm2 reads them)
        if (eh == 0) { half8v z = {}; *(half8v*)&hmid[(size_t)node * D1 + li * 8] = z; }
        return;
    }
    float acc[8] = {0.f, 0.f, 0.f, 0.f, 0.f, 0.f, 0.f, 0.f};
    float den = 0.f;
    if (eh == 0) {                     // self-loop on even half only
        float w0 = expf(lrelu02(asad[(size_t)node * 8 + head] +
                                asad[(size_t)node * 8 + 4 + head]));
        half8v sv = *(const half8v*)&h1[(size_t)node * D1 + li * 8];
        #pragma unroll
        for (int i = 0; i < 8; ++i) acc[i] = (float)sv[i] * w0;
        den = w0;
    }
    const int beg = rowStart[node], end = rowStart[node + 1];
    int j = beg;
    for (; j + 7 < end; j += 8) {      // 8 edges per iter (4 pairs)
        int e0 = j + eh, e1 = j + 2 + eh, e2 = j + 4 + eh, e3 = j + 6 + eh;
        int s0 = sd[e0].x, s1 = sd[e1].x, s2 = sd[e2].x, s3 = sd[e3].x;
        float w0 = (float)wE1[(size_t)e0 * 4 + head];
        float w1 = (float)wE1[(size_t)e1 * 4 + head];
        float w2 = (float)wE1[(size_t)e2 * 4 + head];
        float w3 = (float)wE1[(size_t)e3 * 4 + head];
        half8v r0 = *(const half8v*)&h1[(size_t)s0 * D1 + li * 8];
        half8v r1 = *(const half8v*)&h1[(size_t)s1 * D1 + li * 8];
        half8v r2 = *(const half8v*)&h1[(size_t)s2 * D1 + li * 8];
        half8v r3 = *(const half8v*)&h1[(size_t)s3 * D1 + li * 8];
        #pragma unroll
        for (int i = 0; i < 8; ++i) {
            acc[i] = fmaf((float)r0[i], w0, acc[i]);
            acc[i] = fmaf((float)r1[i], w1, acc[i]);
            acc[i] = fmaf((float)r2[i], w2, acc[i]);
            acc[i] = fmaf((float)r3[i], w3, acc[i]);
        }
        den += w0 + w1 + w2 + w3;
    }
    for (; j < end; j += 2) {          // pair tail (predicated)
        int e = j + eh;
        bool v = e < end;
        int s = v ? sd[e].x : 0;
        float w = v ? (float)wE1[(size_t)e * 4 + head] : 0.f;
        half8v r = *(const half8v*)&h1[(size_t)s * D1 + li * 8];
        #pragma unroll
        for (int i = 0; i < 8; ++i) acc[i] = fmaf((float)r[i], w, acc[i]);
        den += w;
    }
    // combine the two edge-halves
    #pragma unroll
    for (int i = 0; i < 8; ++i) acc[i] += __shfl_xor(acc[i], 32, 64);
    den += __shfl_xor(den, 32, 64);
    float inv = 1.f / (den + 1e-16f);
    float4 bv0 = *(const float4*)&b1[li * 8];
    float4 bv1 = *(const float4*)&b1[li * 8 + 4];
    float y[8];
    y[0] = acc[0] * inv + bv0.x; y[1] = acc[1] * inv + bv0.y;
    y[2] = acc[2] * inv + bv0.z; y[3] = acc[3] * inv + bv0.w;
    y[4] = acc[4] * inv + bv1.x; y[5] = acc[5] * inv + bv1.y;
    y[6] = acc[6] * inv + bv1.z; y[7] = acc[7] * inv + bv1.w;
    float s = y[0] + y[1] + y[2] + y[3] + y[4] + y[5] + y[6] + y[7];
    #pragma unroll
    for (int off = 1; off < 32; off <<= 1) s += __shfl_xor(s, off, 64);
    float mu = s * (1.f / 256.f);
    float dx[8], sq = 0.f;
    #pragma unroll
    for (int i = 0; i < 8; ++i) { dx[i] = y[i] - mu; sq = fmaf(dx[i], dx[i], sq); }
    #pragma unroll
    for (int off = 1; off < 32; off <<= 1) sq += __shfl_xor(sq, off, 64);
    float rs = rsqrtf(sq * (1.f / 256.f) + 1e-5f);
    if (eh == 0) {
        float4 g0 = *(const float4*)&gamma[li * 8];
        float4 g1 = *(const float4*)&gamma[li * 8 + 4];
        float4 be0 = *(const float4*)&beta[li * 8];
        float4 be1 = *(const float4*)&beta[li * 8 + 4];
        half8v o;
        o[0] = (h16)lrelu001(dx[0] * rs * g0.x + be0.x);
        o[1] = (h16)lrelu001(dx[1] * rs * g0.y + be0.y);
        o[2] = (h16)lrelu001(dx[2] * rs * g0.z + be0.z);
        o[3] = (h16)lrelu001(dx[3] * rs * g0.w + be0.w);
        o[4] = (h16)lrelu001(dx[4] * rs * g1.x + be1.x);
        o[5] = (h16)lrelu001(dx[5] * rs * g1.y + be1.y);
        o[6] = (h16)lrelu001(dx[6] * rs * g1.z + be1.z);
        o[7] = (h16)lrelu001(dx[7] * rs * g1.w + be1.w);
        *(half8v*)&hmid[(size_t)node * D1 + li * 8] = o;
    }
}

// ---- gather2: wave per dst node; 4 edges in parallel (16 lanes x 8B);
//      edge weights computed inline (only needs asad2[src] + invariant dst term) ----
__global__ __launch_bounds__(256) void gather2_kernel(const h16* __restrict__ h2,
                                                      const float* __restrict__ asad2,
                                                      const int* __restrict__ rowStart,
                                                      const int2* __restrict__ sd,
                                                      const float* __restrict__ b2,
                                                      float* __restrict__ out, int n) {
    const int lane = threadIdx.x & 63;
    const int node = (blockIdx.x * 256 + threadIdx.x) >> 6;
    if (node >= n) return;
    const int li = lane & 15, eh = lane >> 4;
    const int c0 = li * 4;
    const float ad_n = asad2[(size_t)node * 2 + 1];
    float acc[4] = {0.f, 0.f, 0.f, 0.f};
    float den = 0.f;
    if (eh == 0) {                     // self-loop
        float w0 = expf(lrelu02(asad2[(size_t)node * 2] + ad_n));
        half4v sv = *(const half4v*)&h2[(size_t)node * HID + c0];
        #pragma unroll
        for (int i = 0; i < 4; ++i) acc[i] = (float)sv[i] * w0;
        den = w0;
    }
    const int beg = rowStart[node], end = rowStart[node + 1];
    int j = beg;
    for (; j + 7 < end; j += 8) {      // 8 edges per iter (2 quads)
        int e0 = j + eh, e1 = j + 4 + eh;
        int s0 = sd[e0].x, s1 = sd[e1].x;
        float a0 = asad2[(size_t)s0 * 2], a1 = asad2[(size_t)s1 * 2];
        half4v r0 = *(const half4v*)&h2[(size_t)s0 * HID + c0];
        half4v r1 = *(const half4v*)&h2[(size_t)s1 * HID + c0];
        float w0 = expf(lrelu02(a0 + ad_n));
        float w1 = expf(lrelu02(a1 + ad_n));
        #pragma unroll
        for (int i = 0; i < 4; ++i) {
            acc[i] = fmaf((float)r0[i], w0, acc[i]);
            acc[i] = fmaf((float)r1[i], w1, acc[i]);
        }
        den += w0 + w1;
    }
    for (; j < end; j += 4) {          // quad tail (predicated)
        int e = j + eh;
        bool v = e < end;
        int s = v ? sd[e].x : 0;
        float w = v ? expf(lrelu02(asad2[(size_t)s * 2] + ad_n)) : 0.f;
        half4v r = *(const half4v*)&h2[(size_t)s * HID + c0];
        #pragma unroll
        for (int i = 0; i < 4; ++i) acc[i] = fmaf((float)r[i], w, acc[i]);
        den += w;
    }
    // combine 4 edge-quads
    #pragma unroll
    for (int i = 0; i < 4; ++i) {
        acc[i] += __shfl_xor(acc[i], 32, 64);
        acc[i] += __shfl_xor(acc[i], 16, 64);
    }
    den += __shfl_xor(den, 32, 64);
    den += __shfl_xor(den, 16, 64);
    if (lane < 16) {
        float inv = 1.f / (den + 1e-16f);
        float4 bv = *(const float4*)&b2[c0];
        float4 o;
        o.x = acc[0] * inv + bv.x;
        o.y = acc[1] * inv + bv.y;
        o.z = acc[2] * inv + bv.z;
        o.w = acc[3] * inv + bv.w;
        *(float4*)&out[(size_t)node * HID + c0] = o;
    }
}

extern "C" void kernel_launch(void* const* d_in, const int* in_sizes, int n_in,
                              void* d_out, int out_size, void* d_ws, size_t ws_size,
                              hipStream_t stream) {
    const float* x      = (const float*)d_in[0];
    const int*   ei     = (const int*)d_in[1];
    const float* W1     = (const float*)d_in[2];
    const float* a_src1 = (const float*)d_in[3];
    const float* a_dst1 = (const float*)d_in[4];
    const float* b1     = (const float*)d_in[5];
    const float* gamma  = (const float*)d_in[6];
    const float* beta   = (const float*)d_in[7];
    const float* W2     = (const float*)d_in[8];
    const float* a_src2 = (const float*)d_in[9];
    const float* a_dst2 = (const float*)d_in[10];
    const float* b2     = (const float*)d_in[11];
    float* out = (float*)d_out;

    const int N = in_sizes[0] / IN_CH;
    const int E = in_sizes[1] / 2;
    const int NP = (N + 63) & ~63;          // row-pad for 64-row MFMA tiles

    // workspace layout (float slots; all segment sizes even -> int2 stays 8B-aligned)
    float* ws = (float*)d_ws;
    size_t off = 0;
    h16*   xh   = (h16*)(ws + off); off += (size_t)64 * NP;    // [NP][128] halfs
    h16*   h1   = (h16*)(ws + off); off += (size_t)128 * N;    // [N][256] halfs
    h16*   hmid = (h16*)(ws + off); off += (size_t)128 * NP;   // [NP][256] halfs
    h16*   h2   = (h16*)(ws + off); off += (size_t)32 * N;     // [N][64] halfs
    float* asad = ws + off;         off += (size_t)8 * N;      // [N][8]
    float* asad2= ws + off;         off += (size_t)2 * N;      // [N][2]
    h16*   wE1  = (h16*)(ws + off); off += (size_t)2 * E;      // [E][4] halfs
    int2*  sd   = (int2*)(ws + off); off += (size_t)2 * E;     // [E] (src,dst)
    int* rowStart  = (int*)(ws + off); off += N + 1;
    int* cursor    = (int*)(ws + off); off += N;
    int* blockSums = (int*)(ws + off); off += 64;
    h16* w1t = (h16*)(ws + off); off += 17408;                 // [272][128] halfs
    h16* w2t = (h16*)(ws + off); off += 10240;                 // [80][256] halfs

    const int nodeBlocks  = (N + 3) / 4;
    const int nodeBlocksP = (NP + 3) / 4;
    const int nThreadBlocksE = (E + 255) / 256;
    const int scanBlocks = (N + SCAN_BLK - 1) / SCAN_BLK;      // <= 64 for N <= 65536
    const int castBlocks = (int)(((long)NP * IN_CH / 4 + 255) / 256);

    // CSR counters must be zero before hist (inside setup)
    hipMemsetAsync(cursor, 0, (size_t)N * 4, stream);
    setup_kernel<<<4 + castBlocks + nThreadBlocksE, 256, 0, stream>>>(
        x, W1, W2, a_src1, a_dst1, a_src2, a_dst2, ei, cursor,
        xh, w1t, w2t, (long)NP * IN_CH, (long)N * IN_CH, E, castBlocks);
    scan1_kernel<<<scanBlocks, 256, 0, stream>>>(cursor, rowStart, blockSums, N);
    scan23_kernel<<<scanBlocks, 256, 0, stream>>>(rowStart, blockSums, cursor, N, E, scanBlocks);
    scatter_kernel<<<nThreadBlocksE, 256, 0, stream>>>(ei, cursor, sd, E);

    // layer 1
    gemm1_mfma<<<NP / 64, 256, 0, stream>>>(xh, w1t, h1, asad, N);
    ewt1_kernel<<<(4 * E + 255) / 256, 256, 0, stream>>>(sd, asad, wE1, 4 * E);
    gather1_kernel<<<nodeBlocksP, 256, 0, stream>>>(h1, asad, wE1, rowStart, sd,
                                                    b1, gamma, beta, hmid, N, NP);
    // layer 2
    gemm2_mfma<<<NP / 64, 256, 0, stream>>>(hmid, w2t, h2, asad2, N);
    gather2_kernel<<<nodeBlocks, 256, 0, stream>>>(h2, asad2, rowStart, sd,
                                                   b2, out, N);
}

// Round 9
// 276.313 us; speedup vs baseline: 1.0554x; 1.0554x over previous
//
#include <hip/hip_runtime.h>
#include <hip/hip_bf16.h>

#define IN_CH 128
#define D1 256      // HEADS*HID
#define HID 64
#define HEADS 4
#define SCAN_BLK 1024

typedef _Float16 h16;
typedef __attribute__((ext_vector_type(4))) _Float16 half4v;
typedef __attribute__((ext_vector_type(8))) _Float16 half8v;
typedef __attribute__((ext_vector_type(4))) float f32x4;

__device__ __forceinline__ float lrelu02(float v) { return v > 0.f ? v : 0.2f * v; }
__device__ __forceinline__ float lrelu001(float v) { return v > 0.f ? v : 0.01f * v; }

// ---- setup: weight prep (blocks 0..3) | hist (rest) ----
// w1t: [272][128] rows 0..255=W1^T, 256..263=u1 (4 src + 4 dst heads), 264..271=0
// w2t: [80][256]  rows 0..63=W2^T, 64/65=u2 (src,dst), 66..79=0
__global__ __launch_bounds__(256) void setup_kernel(const float* __restrict__ W1,
                                                    const float* __restrict__ W2,
                                                    const float* __restrict__ a_src1,
                                                    const float* __restrict__ a_dst1,
                                                    const float* __restrict__ a_src2,
                                                    const float* __restrict__ a_dst2,
                                                    const int* __restrict__ ei,
                                                    int* __restrict__ cnt,
                                                    h16* __restrict__ w1t,
                                                    h16* __restrict__ w2t,
                                                    int nE) {
    const int b = blockIdx.x;
    const int t = threadIdx.x;
    if (b == 0) {
        for (int k = 0; k < IN_CH; ++k) w1t[t * IN_CH + k] = (h16)W1[k * D1 + t];
    } else if (b == 1) {
        if (t < HID)
            for (int k = 0; k < D1; ++k) w2t[t * D1 + k] = (h16)W2[k * HID + t];
        for (int i = t; i < 14 * D1; i += 256) w2t[66 * D1 + i] = (h16)0.f;
    } else if (b == 2) {
        for (int o = t; o < 1024; o += 256) {
            int v = o >> 7, k = o & 127;
            int h = v & 3;
            const float* avec = (v >> 2) ? (a_dst1 + h * HID) : (a_src1 + h * HID);
            const float* wrow = W1 + k * D1 + h * HID;
            float s = 0.f;
            for (int c = 0; c < HID; ++c) s += wrow[c] * avec[c];
            w1t[(256 + v) * IN_CH + k] = (h16)s;
            w1t[(264 + v) * IN_CH + k] = (h16)0.f;
        }
    } else if (b == 3) {
        for (int o = t; o < 512; o += 256) {
            int v = o >> 8, k = o & 255;
            const float* avec = v ? a_dst2 : a_src2;
            const float* wrow = W2 + k * HID;
            float s = 0.f;
            for (int c = 0; c < HID; ++c) s += wrow[c] * avec[c];
            w2t[(64 + v) * D1 + k] = (h16)s;
        }
    } else {
        int e = (b - 4) * 256 + t;
        if (e < nE) atomicAdd(&cnt[ei[nE + e]], 1);
    }
}

// ---- scan1: per-block exclusive scan (1024 elems), block totals out ----
__global__ __launch_bounds__(256) void scan1_kernel(const int* __restrict__ cnt,
                                                    int* __restrict__ pre,
                                                    int* __restrict__ blockSums, int n) {
    __shared__ int lds[256];
    const int t = threadIdx.x;
    const int base = blockIdx.x * SCAN_BLK + t * 4;
    int v0 = 0, v1 = 0, v2 = 0, v3 = 0;
    if (base + 0 < n) v0 = cnt[base + 0];
    if (base + 1 < n) v1 = cnt[base + 1];
    if (base + 2 < n) v2 = cnt[base + 2];
    if (base + 3 < n) v3 = cnt[base + 3];
    int s = v0 + v1 + v2 + v3;
    lds[t] = s;
    __syncthreads();
    for (int off = 1; off < 256; off <<= 1) {
        int x = 0;
        if (t >= off) x = lds[t - off];
        __syncthreads();
        if (t >= off) lds[t] += x;
        __syncthreads();
    }
    int excl = lds[t] - s;
    if (t == 255) blockSums[blockIdx.x] = lds[255];
    if (base + 0 < n) pre[base + 0] = excl;
    if (base + 1 < n) pre[base + 1] = excl + v0;
    if (base + 2 < n) pre[base + 2] = excl + v0 + v1;
    if (base + 3 < n) pre[base + 3] = excl + v0 + v1 + v2;
}

// ---- scan23: add block offsets (wave-parallel partial sum of blockSums) ----
__global__ __launch_bounds__(256) void scan23_kernel(int* __restrict__ pre,
                                                     const int* __restrict__ blockSums,
                                                     int* __restrict__ cursor,
                                                     int n, int nE, int nb) {
    __shared__ int soff_s;
    const int t = threadIdx.x;
    if (t < 64) {
        int v = (t < blockIdx.x && t < nb) ? blockSums[t] : 0;   // nb <= 64
        #pragma unroll
        for (int off = 1; off < 64; off <<= 1) v += __shfl_xor(v, off, 64);
        if (t == 0) soff_s = v;
    }
    __syncthreads();
    const int soff = soff_s;
    const int base = blockIdx.x * SCAN_BLK + t * 4;
    #pragma unroll
    for (int q = 0; q < 4; ++q) {
        int i = base + q;
        if (i < n) {
            int v = pre[i] + soff;
            pre[i] = v;
            cursor[i] = v;
        }
    }
    if (blockIdx.x == 0 && t == 0) pre[n] = nE;
}

__global__ __launch_bounds__(256) void scatter_kernel(const int* __restrict__ ei,
                                                      int* __restrict__ cursor,
                                                      int* __restrict__ srcIdx, int nE) {
    int e = blockIdx.x * 256 + threadIdx.x;
    if (e >= nE) return;
    int src = ei[e];
    int dst = ei[nE + e];
    int pos = atomicAdd(&cursor[dst], 1);
    srcIdx[pos] = src;
}

// ---- MFMA GEMM1: h1[N,256](fp16) + asad[N,8] = cast16(x[N,128]) @ w1t ----
__global__ __launch_bounds__(256) void gemm1_mfma(const float* __restrict__ x,
                                                  const h16* __restrict__ w1t,
                                                  h16* __restrict__ h1,
                                                  float* __restrict__ asad, int n) {
    const int wave = threadIdx.x >> 6, lane = threadIdx.x & 63;
    const int r = lane & 15, ksel = lane >> 4;
    const int rowBase = blockIdx.x * 64 + wave * 16;
    const int row_a = rowBase + r;
    half8v a[4];
    if (row_a < n) {
        const float* xrow = x + (size_t)row_a * IN_CH + ksel * 8;
        #pragma unroll
        for (int kk = 0; kk < 4; ++kk) {
            float4 u = *(const float4*)(xrow + kk * 32);
            float4 v = *(const float4*)(xrow + kk * 32 + 4);
            half8v av;
            av[0] = (h16)u.x; av[1] = (h16)u.y; av[2] = (h16)u.z; av[3] = (h16)u.w;
            av[4] = (h16)v.x; av[5] = (h16)v.y; av[6] = (h16)v.z; av[7] = (h16)v.w;
            a[kk] = av;
        }
    } else {
        #pragma unroll
        for (int kk = 0; kk < 4; ++kk) a[kk] = (half8v){};
    }
    f32x4 acc[17];
    #pragma unroll
    for (int ct = 0; ct < 17; ++ct) acc[ct] = (f32x4){0.f, 0.f, 0.f, 0.f};
    #pragma unroll
    for (int ct = 0; ct < 17; ++ct) {
        const h16* wrow = w1t + (size_t)(ct * 16 + r) * IN_CH + ksel * 8;
        #pragma unroll
        for (int kk = 0; kk < 4; ++kk) {
            half8v b = *(const half8v*)(wrow + kk * 32);
            acc[ct] = __builtin_amdgcn_mfma_f32_16x16x32_f16(a[kk], b, acc[ct], 0, 0, 0);
        }
    }
    #pragma unroll
    for (int i = 0; i < 4; ++i) {
        int row = rowBase + ksel * 4 + i;
        if (row < n) {
            #pragma unroll
            for (int ct = 0; ct < 16; ++ct)
                h1[(size_t)row * D1 + ct * 16 + r] = (h16)acc[ct][i];
            if (r < 8) asad[(size_t)row * 8 + r] = acc[16][i];
        }
    }
}

// ---- MFMA GEMM2: h2[N,64](fp16) + asad2[N,2] = hmid[NP,256] @ w2t ----
__global__ __launch_bounds__(256) void gemm2_mfma(const h16* __restrict__ hm,
                                                  const h16* __restrict__ w2t,
                                                  h16* __restrict__ h2,
                                                  float* __restrict__ asad2, int n) {
    const int wave = threadIdx.x >> 6, lane = threadIdx.x & 63;
    const int r = lane & 15, ksel = lane >> 4;
    const int rowBase = blockIdx.x * 64 + wave * 16;
    const h16* xrow = hm + (size_t)(rowBase + r) * D1 + ksel * 8;
    half8v a[8];
    #pragma unroll
    for (int kk = 0; kk < 8; ++kk) a[kk] = *(const half8v*)(xrow + kk * 32);
    f32x4 acc[5];
    #pragma unroll
    for (int ct = 0; ct < 5; ++ct) acc[ct] = (f32x4){0.f, 0.f, 0.f, 0.f};
    #pragma unroll
    for (int ct = 0; ct < 5; ++ct) {
        const h16* wrow = w2t + (size_t)(ct * 16 + r) * D1 + ksel * 8;
        #pragma unroll
        for (int kk = 0; kk < 8; ++kk) {
            half8v b = *(const half8v*)(wrow + kk * 32);
            acc[ct] = __builtin_amdgcn_mfma_f32_16x16x32_f16(a[kk], b, acc[ct], 0, 0, 0);
        }
    }
    #pragma unroll
    for (int i = 0; i < 4; ++i) {
        int row = rowBase + ksel * 4 + i;
        if (row < n) {
            #pragma unroll
            for (int ct = 0; ct < 4; ++ct)
                h2[(size_t)row * HID + ct * 16 + r] = (h16)acc[ct][i];
            if (r < 2) asad2[(size_t)row * 2 + r] = acc[4][i];
        }
    }
}

// ---- gather1: wave per dst node; inline edge weights; fused bias+LN+lrelu; fp16 out ----
__global__ __launch_bounds__(256) void gather1_kernel(const h16* __restrict__ h1,
                                                      const float* __restrict__ asad,
                                                      const int* __restrict__ rowStart,
                                                      const int* __restrict__ srcIdx,
                                                      const float* __restrict__ b1,
                                                      const float* __restrict__ gamma,
                                                      const float* __restrict__ beta,
                                                      h16* __restrict__ hmid, int n, int npad) {
    const int lane = threadIdx.x & 63;
    const int node = (blockIdx.x * 256 + threadIdx.x) >> 6;
    if (node >= npad) return;
    if (node >= n) {            // zero pad rows (gemm2 reads them)
        half4v z = {};
        *(half4v*)&hmid[(size_t)node * D1 + lane * 4] = z;
        return;
    }
    const int hh = lane >> 4;
    const float ad_h = asad[(size_t)node * 8 + 4 + hh];          // dst term, loop-invariant
    const float w = expf(lrelu02(asad[(size_t)node * 8 + hh] + ad_h));  // self-loop
    half4v sv = *(const half4v*)&h1[(size_t)node * D1 + lane * 4];
    float4 acc = make_float4((float)sv.x * w, (float)sv.y * w,
                             (float)sv.z * w, (float)sv.w * w);
    float den = w;
    const int beg = rowStart[node], end = rowStart[node + 1];
    int j = beg;
    for (; j + 7 < end; j += 8) {
        int sI[8]; float wv[8]; half4v rv[8];
        #pragma unroll
        for (int q = 0; q < 8; ++q) sI[q] = srcIdx[j + q];
        #pragma unroll
        for (int q = 0; q < 8; ++q)
            wv[q] = expf(lrelu02(asad[(size_t)sI[q] * 8 + hh] + ad_h));
        #pragma unroll
        for (int q = 0; q < 8; ++q) rv[q] = *(const half4v*)&h1[(size_t)sI[q] * D1 + lane * 4];
        #pragma unroll
        for (int q = 0; q < 8; ++q) {
            acc.x = fmaf((float)rv[q].x, wv[q], acc.x);
            acc.y = fmaf((float)rv[q].y, wv[q], acc.y);
            acc.z = fmaf((float)rv[q].z, wv[q], acc.z);
            acc.w = fmaf((float)rv[q].w, wv[q], acc.w);
            den += wv[q];
        }
    }
    for (; j + 3 < end; j += 4) {
        int sI[4]; float wv[4]; half4v rv[4];
        #pragma unroll
        for (int q = 0; q < 4; ++q) sI[q] = srcIdx[j + q];
        #pragma unroll
        for (int q = 0; q < 4; ++q)
            wv[q] = expf(lrelu02(asad[(size_t)sI[q] * 8 + hh] + ad_h));
        #pragma unroll
        for (int q = 0; q < 4; ++q) rv[q] = *(const half4v*)&h1[(size_t)sI[q] * D1 + lane * 4];
        #pragma unroll
        for (int q = 0; q < 4; ++q) {
            acc.x = fmaf((float)rv[q].x, wv[q], acc.x);
            acc.y = fmaf((float)rv[q].y, wv[q], acc.y);
            acc.z = fmaf((float)rv[q].z, wv[q], acc.z);
            acc.w = fmaf((float)rv[q].w, wv[q], acc.w);
            den += wv[q];
        }
    }
    for (; j < end; ++j) {
        int s = srcIdx[j];
        float wj = expf(lrelu02(asad[(size_t)s * 8 + hh] + ad_h));
        half4v xv = *(const half4v*)&h1[(size_t)s * D1 + lane * 4];
        acc.x = fmaf((float)xv.x, wj, acc.x);
        acc.y = fmaf((float)xv.y, wj, acc.y);
        acc.z = fmaf((float)xv.z, wj, acc.z);
        acc.w = fmaf((float)xv.w, wj, acc.w);
        den += wj;
    }
    float inv = 1.f / (den + 1e-16f);
    float4 bv = *(const float4*)&b1[lane * 4];
    float4 y;
    y.x = acc.x * inv + bv.x; y.y = acc.y * inv + bv.y;
    y.z = acc.z * inv + bv.z; y.w = acc.w * inv + bv.w;
    float s = y.x + y.y + y.z + y.w;
    #pragma unroll
    for (int off = 1; off < 64; off <<= 1) s += __shfl_xor(s, off, 64);
    float mu = s * (1.f / 256.f);
    float4 dx;
    dx.x = y.x - mu; dx.y = y.y - mu; dx.z = y.z - mu; dx.w = y.w - mu;
    float sq = dx.x * dx.x + dx.y * dx.y + dx.z * dx.z + dx.w * dx.w;
    #pragma unroll
    for (int off = 1; off < 64; off <<= 1) sq += __shfl_xor(sq, off, 64);
    float rs = rsqrtf(sq * (1.f / 256.f) + 1e-5f);
    float4 g = *(const float4*)&gamma[lane * 4];
    float4 be = *(const float4*)&beta[lane * 4];
    half4v o;
    o.x = (h16)lrelu001(dx.x * rs * g.x + be.x);
    o.y = (h16)lrelu001(dx.y * rs * g.y + be.y);
    o.z = (h16)lrelu001(dx.z * rs * g.z + be.z);
    o.w = (h16)lrelu001(dx.w * rs * g.w + be.w);
    *(half4v*)&hmid[(size_t)node * D1 + lane * 4] = o;
}

// ---- gather2: wave per dst node; 4 edges in parallel (16 lanes x 8B); inline weights ----
__global__ __launch_bounds__(256) void gather2_kernel(const h16* __restrict__ h2,
                                                      const float* __restrict__ asad2,
                                                      const int* __restrict__ rowStart,
                                                      const int* __restrict__ srcIdx,
                                                      const float* __restrict__ b2,
                                                      float* __restrict__ out, int n) {
    const int lane = threadIdx.x & 63;
    const int node = (blockIdx.x * 256 + threadIdx.x) >> 6;
    if (node >= n) return;
    const int li = lane & 15, eh = lane >> 4;
    const int c0 = li * 4;
    const float ad_n = asad2[(size_t)node * 2 + 1];
    float acc[4] = {0.f, 0.f, 0.f, 0.f};
    float den = 0.f;
    if (eh == 0) {                     // self-loop
        float w0 = expf(lrelu02(asad2[(size_t)node * 2] + ad_n));
        half4v sv = *(const half4v*)&h2[(size_t)node * HID + c0];
        #pragma unroll
        for (int i = 0; i < 4; ++i) acc[i] = (float)sv[i] * w0;
        den = w0;
    }
    const int beg = rowStart[node], end = rowStart[node + 1];
    int j = beg;
    for (; j + 7 < end; j += 8) {      // 8 edges per iter (2 quads)
        int e0 = j + eh, e1 = j + 4 + eh;
        int s0 = srcIdx[e0], s1 = srcIdx[e1];
        float a0 = asad2[(size_t)s0 * 2], a1 = asad2[(size_t)s1 * 2];
        half4v r0 = *(const half4v*)&h2[(size_t)s0 * HID + c0];
        half4v r1 = *(const half4v*)&h2[(size_t)s1 * HID + c0];
        float w0 = expf(lrelu02(a0 + ad_n));
        float w1 = expf(lrelu02(a1 + ad_n));
        #pragma unroll
        for (int i = 0; i < 4; ++i) {
            acc[i] = fmaf((float)r0[i], w0, acc[i]);
            acc[i] = fmaf((float)r1[i], w1, acc[i]);
        }
        den += w0 + w1;
    }
    for (; j < end; j += 4) {          // quad tail (predicated)
        int e = j + eh;
        bool v = e < end;
        int s = v ? srcIdx[e] : 0;
        float w = v ? expf(lrelu02(asad2[(size_t)s * 2] + ad_n)) : 0.f;
        half4v r = *(const half4v*)&h2[(size_t)s * HID + c0];
        #pragma unroll
        for (int i = 0; i < 4; ++i) acc[i] = fmaf((float)r[i], w, acc[i]);
        den += w;
    }
    #pragma unroll
    for (int i = 0; i < 4; ++i) {
        acc[i] += __shfl_xor(acc[i], 32, 64);
        acc[i] += __shfl_xor(acc[i], 16, 64);
    }
    den += __shfl_xor(den, 32, 64);
    den += __shfl_xor(den, 16, 64);
    if (lane < 16) {
        float inv = 1.f / (den + 1e-16f);
        float4 bv = *(const float4*)&b2[c0];
        float4 o;
        o.x = acc[0] * inv + bv.x;
        o.y = acc[1] * inv + bv.y;
        o.z = acc[2] * inv + bv.z;
        o.w = acc[3] * inv + bv.w;
        *(float4*)&out[(size_t)node * HID + c0] = o;
    }
}

extern "C" void kernel_launch(void* const* d_in, const int* in_sizes, int n_in,
                              void* d_out, int out_size, void* d_ws, size_t ws_size,
                              hipStream_t stream) {
    const float* x      = (const float*)d_in[0];
    const int*   ei     = (const int*)d_in[1];
    const float* W1     = (const float*)d_in[2];
    const float* a_src1 = (const float*)d_in[3];
    const float* a_dst1 = (const float*)d_in[4];
    const float* b1     = (const float*)d_in[5];
    const float* gamma  = (const float*)d_in[6];
    const float* beta   = (const float*)d_in[7];
    const float* W2     = (const float*)d_in[8];
    const float* a_src2 = (const float*)d_in[9];
    const float* a_dst2 = (const float*)d_in[10];
    const float* b2     = (const float*)d_in[11];
    float* out = (float*)d_out;

    const int N = in_sizes[0] / IN_CH;
    const int E = in_sizes[1] / 2;
    const int NP = (N + 63) & ~63;          // row-pad for 64-row MFMA tiles

    // workspace layout (float slots)
    float* ws = (float*)d_ws;
    size_t off = 0;
    h16*   h1   = (h16*)(ws + off); off += (size_t)128 * N;    // [N][256] halfs
    h16*   hmid = (h16*)(ws + off); off += (size_t)128 * NP;   // [NP][256] halfs
    h16*   h2   = (h16*)(ws + off); off += (size_t)32 * N;     // [N][64] halfs
    float* asad = ws + off;         off += (size_t)8 * N;      // [N][8]
    float* asad2= ws + off;         off += (size_t)2 * N;      // [N][2]
    int* srcIdx    = (int*)(ws + off); off += E;
    int* rowStart  = (int*)(ws + off); off += N + 1;
    int* cursor    = (int*)(ws + off); off += N;
    int* blockSums = (int*)(ws + off); off += 64;
    h16* w1t = (h16*)(ws + off); off += 17408;                 // [272][128] halfs
    h16* w2t = (h16*)(ws + off); off += 10240;                 // [80][256] halfs

    const int nodeBlocks  = (N + 3) / 4;
    const int nodeBlocksP = (NP + 3) / 4;
    const int nThreadBlocksE = (E + 255) / 256;
    const int scanBlocks = (N + SCAN_BLK - 1) / SCAN_BLK;      // <= 64 for N <= 65536

    // CSR counters must be zero before hist (inside setup)
    hipMemsetAsync(cursor, 0, (size_t)N * 4, stream);
    setup_kernel<<<4 + nThreadBlocksE, 256, 0, stream>>>(
        W1, W2, a_src1, a_dst1, a_src2, a_dst2, ei, cursor, w1t, w2t, E);
    scan1_kernel<<<scanBlocks, 256, 0, stream>>>(cursor, rowStart, blockSums, N);
    scan23_kernel<<<scanBlocks, 256, 0, stream>>>(rowStart, blockSums, cursor, N, E, scanBlocks);
    scatter_kernel<<<nThreadBlocksE, 256, 0, stream>>>(ei, cursor, srcIdx, E);

    // layer 1
    gemm1_mfma<<<NP / 64, 256, 0, stream>>>(x, w1t, h1, asad, N);
    gather1_kernel<<<nodeBlocksP, 256, 0, stream>>>(h1, asad, rowStart, srcIdx,
                                                    b1, gamma, beta, hmid, N, NP);
    // layer 2
    gemm2_mfma<<<NP / 64, 256, 0, stream>>>(hmid, w2t, h2, asad2, N);
    gather2_kernel<<<nodeBlocks, 256, 0, stream>>>(h2, asad2, rowStart, srcIdx,
                                                   b2, out, N);
}

// Round 10
// 261.631 us; speedup vs baseline: 1.1147x; 1.0561x over previous
//
#include <hip/hip_runtime.h>
#include <hip/hip_bf16.h>

#define IN_CH 128
#define D1 256      // HEADS*HID
#define HID 64
#define HEADS 4
#define SCAN_BLK 1024

typedef _Float16 h16;
typedef __attribute__((ext_vector_type(4))) _Float16 half4v;
typedef __attribute__((ext_vector_type(8))) _Float16 half8v;
typedef __attribute__((ext_vector_type(4))) float f32x4;

__device__ __forceinline__ float lrelu02(float v) { return v > 0.f ? v : 0.2f * v; }
__device__ __forceinline__ float lrelu001(float v) { return v > 0.f ? v : 0.01f * v; }

// ---- setup: weight prep (blocks 0..3) | hist (rest) ----
// w1t: [272][128] rows 0..255=W1^T, 256..263=u1 (4 src + 4 dst heads), 264..271=0
// w2t: [80][256]  rows 0..63=W2^T, 64/65=u2 (src,dst), 66..79=0
__global__ __launch_bounds__(256) void setup_kernel(const float* __restrict__ W1,
                                                    const float* __restrict__ W2,
                                                    const float* __restrict__ a_src1,
                                                    const float* __restrict__ a_dst1,
                                                    const float* __restrict__ a_src2,
                                                    const float* __restrict__ a_dst2,
                                                    const int* __restrict__ ei,
                                                    int* __restrict__ cnt,
                                                    h16* __restrict__ w1t,
                                                    h16* __restrict__ w2t,
                                                    int nE) {
    const int b = blockIdx.x;
    const int t = threadIdx.x;
    if (b == 0) {
        for (int k = 0; k < IN_CH; ++k) w1t[t * IN_CH + k] = (h16)W1[k * D1 + t];
    } else if (b == 1) {
        if (t < HID)
            for (int k = 0; k < D1; ++k) w2t[t * D1 + k] = (h16)W2[k * HID + t];
        for (int i = t; i < 14 * D1; i += 256) w2t[66 * D1 + i] = (h16)0.f;
    } else if (b == 2) {
        for (int o = t; o < 1024; o += 256) {
            int v = o >> 7, k = o & 127;
            int h = v & 3;
            const float* avec = (v >> 2) ? (a_dst1 + h * HID) : (a_src1 + h * HID);
            const float* wrow = W1 + k * D1 + h * HID;
            float s = 0.f;
            for (int c = 0; c < HID; ++c) s += wrow[c] * avec[c];
            w1t[(256 + v) * IN_CH + k] = (h16)s;
            w1t[(264 + v) * IN_CH + k] = (h16)0.f;
        }
    } else if (b == 3) {
        for (int o = t; o < 512; o += 256) {
            int v = o >> 8, k = o & 255;
            const float* avec = v ? a_dst2 : a_src2;
            const float* wrow = W2 + k * HID;
            float s = 0.f;
            for (int c = 0; c < HID; ++c) s += wrow[c] * avec[c];
            w2t[(64 + v) * D1 + k] = (h16)s;
        }
    } else {
        int e = (b - 4) * 256 + t;
        if (e < nE) atomicAdd(&cnt[ei[nE + e]], 1);
    }
}

// ---- scan1: per-block exclusive scan (1024 elems), block totals out ----
__global__ __launch_bounds__(256) void scan1_kernel(const int* __restrict__ cnt,
                                                    int* __restrict__ pre,
                                                    int* __restrict__ blockSums, int n) {
    __shared__ int lds[256];
    const int t = threadIdx.x;
    const int base = blockIdx.x * SCAN_BLK + t * 4;
    int v0 = 0, v1 = 0, v2 = 0, v3 = 0;
    if (base + 0 < n) v0 = cnt[base + 0];
    if (base + 1 < n) v1 = cnt[base + 1];
    if (base + 2 < n) v2 = cnt[base + 2];
    if (base + 3 < n) v3 = cnt[base + 3];
    int s = v0 + v1 + v2 + v3;
    lds[t] = s;
    __syncthreads();
    for (int off = 1; off < 256; off <<= 1) {
        int x = 0;
        if (t >= off) x = lds[t - off];
        __syncthreads();
        if (t >= off) lds[t] += x;
        __syncthreads();
    }
    int excl = lds[t] - s;
    if (t == 255) blockSums[blockIdx.x] = lds[255];
    if (base + 0 < n) pre[base + 0] = excl;
    if (base + 1 < n) pre[base + 1] = excl + v0;
    if (base + 2 < n) pre[base + 2] = excl + v0 + v1;
    if (base + 3 < n) pre[base + 3] = excl + v0 + v1 + v2;
}

// ---- scan23: add block offsets (wave-parallel partial sum of blockSums) ----
__global__ __launch_bounds__(256) void scan23_kernel(int* __restrict__ pre,
                                                     const int* __restrict__ blockSums,
                                                     int* __restrict__ cursor,
                                                     int n, int nE, int nb) {
    __shared__ int soff_s;
    const int t = threadIdx.x;
    if (t < 64) {
        int v = (t < blockIdx.x && t < nb) ? blockSums[t] : 0;   // nb <= 64
        #pragma unroll
        for (int off = 1; off < 64; off <<= 1) v += __shfl_xor(v, off, 64);
        if (t == 0) soff_s = v;
    }
    __syncthreads();
    const int soff = soff_s;
    const int base = blockIdx.x * SCAN_BLK + t * 4;
    #pragma unroll
    for (int q = 0; q < 4; ++q) {
        int i = base + q;
        if (i < n) {
            int v = pre[i] + soff;
            pre[i] = v;
            cursor[i] = v;
        }
    }
    if (blockIdx.x == 0 && t == 0) pre[n] = nE;
}

// ---- scatter_ewt: CSR scatter + layer-1 edge weights in one pass (runs after gemm1) ----
__global__ __launch_bounds__(256) void scatter_ewt_kernel(const int* __restrict__ ei,
                                                          int* __restrict__ cursor,
                                                          const float* __restrict__ asad,
                                                          int* __restrict__ srcIdx,
                                                          h16* __restrict__ wE1, int nE) {
    int e = blockIdx.x * 256 + threadIdx.x;
    if (e >= nE) return;
    int src = ei[e];
    int dst = ei[nE + e];
    int pos = atomicAdd(&cursor[dst], 1);
    srcIdx[pos] = src;
    float4 as = *(const float4*)&asad[(size_t)src * 8];
    float4 ad = *(const float4*)&asad[(size_t)dst * 8 + 4];
    half4v w;
    w.x = (h16)expf(lrelu02(as.x + ad.x));
    w.y = (h16)expf(lrelu02(as.y + ad.y));
    w.z = (h16)expf(lrelu02(as.z + ad.z));
    w.w = (h16)expf(lrelu02(as.w + ad.w));
    *(half4v*)&wE1[(size_t)pos * 4] = w;
}

// ---- MFMA GEMM1: h1[N,256](fp16) + asad[N,8] = cast16(x[N,128]) @ w1t ----
__global__ __launch_bounds__(256) void gemm1_mfma(const float* __restrict__ x,
                                                  const h16* __restrict__ w1t,
                                                  h16* __restrict__ h1,
                                                  float* __restrict__ asad, int n) {
    const int wave = threadIdx.x >> 6, lane = threadIdx.x & 63;
    const int r = lane & 15, ksel = lane >> 4;
    const int rowBase = blockIdx.x * 64 + wave * 16;
    const int row_a = rowBase + r;
    half8v a[4];
    if (row_a < n) {
        const float* xrow = x + (size_t)row_a * IN_CH + ksel * 8;
        #pragma unroll
        for (int kk = 0; kk < 4; ++kk) {
            float4 u = *(const float4*)(xrow + kk * 32);
            float4 v = *(const float4*)(xrow + kk * 32 + 4);
            half8v av;
            av[0] = (h16)u.x; av[1] = (h16)u.y; av[2] = (h16)u.z; av[3] = (h16)u.w;
            av[4] = (h16)v.x; av[5] = (h16)v.y; av[6] = (h16)v.z; av[7] = (h16)v.w;
            a[kk] = av;
        }
    } else {
        #pragma unroll
        for (int kk = 0; kk < 4; ++kk) a[kk] = (half8v){};
    }
    f32x4 acc[17];
    #pragma unroll
    for (int ct = 0; ct < 17; ++ct) acc[ct] = (f32x4){0.f, 0.f, 0.f, 0.f};
    #pragma unroll
    for (int ct = 0; ct < 17; ++ct) {
        const h16* wrow = w1t + (size_t)(ct * 16 + r) * IN_CH + ksel * 8;
        #pragma unroll
        for (int kk = 0; kk < 4; ++kk) {
            half8v b = *(const half8v*)(wrow + kk * 32);
            acc[ct] = __builtin_amdgcn_mfma_f32_16x16x32_f16(a[kk], b, acc[ct], 0, 0, 0);
        }
    }
    #pragma unroll
    for (int i = 0; i < 4; ++i) {
        int row = rowBase + ksel * 4 + i;
        if (row < n) {
            #pragma unroll
            for (int ct = 0; ct < 16; ++ct)
                h1[(size_t)row * D1 + ct * 16 + r] = (h16)acc[ct][i];
            if (r < 8) asad[(size_t)row * 8 + r] = acc[16][i];
        }
    }
}

// ---- MFMA GEMM2: h2[N,64](fp16) + asad2[N,2] = hmid[NP,256] @ w2t ----
__global__ __launch_bounds__(256) void gemm2_mfma(const h16* __restrict__ hm,
                                                  const h16* __restrict__ w2t,
                                                  h16* __restrict__ h2,
                                                  float* __restrict__ asad2, int n) {
    const int wave = threadIdx.x >> 6, lane = threadIdx.x & 63;
    const int r = lane & 15, ksel = lane >> 4;
    const int rowBase = blockIdx.x * 64 + wave * 16;
    const h16* xrow = hm + (size_t)(rowBase + r) * D1 + ksel * 8;
    half8v a[8];
    #pragma unroll
    for (int kk = 0; kk < 8; ++kk) a[kk] = *(const half8v*)(xrow + kk * 32);
    f32x4 acc[5];
    #pragma unroll
    for (int ct = 0; ct < 5; ++ct) acc[ct] = (f32x4){0.f, 0.f, 0.f, 0.f};
    #pragma unroll
    for (int ct = 0; ct < 5; ++ct) {
        const h16* wrow = w2t + (size_t)(ct * 16 + r) * D1 + ksel * 8;
        #pragma unroll
        for (int kk = 0; kk < 8; ++kk) {
            half8v b = *(const half8v*)(wrow + kk * 32);
            acc[ct] = __builtin_amdgcn_mfma_f32_16x16x32_f16(a[kk], b, acc[ct], 0, 0, 0);
        }
    }
    #pragma unroll
    for (int i = 0; i < 4; ++i) {
        int row = rowBase + ksel * 4 + i;
        if (row < n) {
            #pragma unroll
            for (int ct = 0; ct < 4; ++ct)
                h2[(size_t)row * HID + ct * 16 + r] = (h16)acc[ct][i];
            if (r < 2) asad2[(size_t)row * 2 + r] = acc[4][i];
        }
    }
}

// ---- gather1: wave per dst node; precomputed fp16 weights; fused bias+LN+lrelu ----
__global__ __launch_bounds__(256) void gather1_kernel(const h16* __restrict__ h1,
                                                      const float* __restrict__ asad,
                                                      const h16* __restrict__ wE1,
                                                      const int* __restrict__ rowStart,
                                                      const int* __restrict__ srcIdx,
                                                      const float* __restrict__ b1,
                                                      const float* __restrict__ gamma,
                                                      const float* __restrict__ beta,
                                                      h16* __restrict__ hmid, int n, int npad) {
    const int lane = threadIdx.x & 63;
    const int node = (blockIdx.x * 256 + threadIdx.x) >> 6;
    if (node >= npad) return;
    if (node >= n) {            // zero pad rows (gemm2 reads them)
        half4v z = {};
        *(half4v*)&hmid[(size_t)node * D1 + lane * 4] = z;
        return;
    }
    const int hh = lane >> 4;
    const float w = expf(lrelu02(asad[(size_t)node * 8 + hh] +
                                 asad[(size_t)node * 8 + 4 + hh]));  // self-loop
    half4v sv = *(const half4v*)&h1[(size_t)node * D1 + lane * 4];
    float4 acc = make_float4((float)sv.x * w, (float)sv.y * w,
                             (float)sv.z * w, (float)sv.w * w);
    float den = w;
    const int beg = rowStart[node], end = rowStart[node + 1];
    int j = beg;
    for (; j + 7 < end; j += 8) {
        int sI[8]; float wv[8]; half4v rv[8];
        #pragma unroll
        for (int q = 0; q < 8; ++q) sI[q] = srcIdx[j + q];
        #pragma unroll
        for (int q = 0; q < 8; ++q) wv[q] = (float)wE1[(size_t)(j + q) * 4 + hh];
        #pragma unroll
        for (int q = 0; q < 8; ++q) rv[q] = *(const half4v*)&h1[(size_t)sI[q] * D1 + lane * 4];
        #pragma unroll
        for (int q = 0; q < 8; ++q) {
            acc.x = fmaf((float)rv[q].x, wv[q], acc.x);
            acc.y = fmaf((float)rv[q].y, wv[q], acc.y);
            acc.z = fmaf((float)rv[q].z, wv[q], acc.z);
            acc.w = fmaf((float)rv[q].w, wv[q], acc.w);
            den += wv[q];
        }
    }
    for (; j + 3 < end; j += 4) {
        int sI[4]; float wv[4]; half4v rv[4];
        #pragma unroll
        for (int q = 0; q < 4; ++q) sI[q] = srcIdx[j + q];
        #pragma unroll
        for (int q = 0; q < 4; ++q) wv[q] = (float)wE1[(size_t)(j + q) * 4 + hh];
        #pragma unroll
        for (int q = 0; q < 4; ++q) rv[q] = *(const half4v*)&h1[(size_t)sI[q] * D1 + lane * 4];
        #pragma unroll
        for (int q = 0; q < 4; ++q) {
            acc.x = fmaf((float)rv[q].x, wv[q], acc.x);
            acc.y = fmaf((float)rv[q].y, wv[q], acc.y);
            acc.z = fmaf((float)rv[q].z, wv[q], acc.z);
            acc.w = fmaf((float)rv[q].w, wv[q], acc.w);
            den += wv[q];
        }
    }
    for (; j < end; ++j) {
        int s = srcIdx[j];
        float wj = (float)wE1[(size_t)j * 4 + hh];
        half4v xv = *(const half4v*)&h1[(size_t)s * D1 + lane * 4];
        acc.x = fmaf((float)xv.x, wj, acc.x);
        acc.y = fmaf((float)xv.y, wj, acc.y);
        acc.z = fmaf((float)xv.z, wj, acc.z);
        acc.w = fmaf((float)xv.w, wj, acc.w);
        den += wj;
    }
    float inv = 1.f / (den + 1e-16f);
    float4 bv = *(const float4*)&b1[lane * 4];
    float4 y;
    y.x = acc.x * inv + bv.x; y.y = acc.y * inv + bv.y;
    y.z = acc.z * inv + bv.z; y.w = acc.w * inv + bv.w;
    float s = y.x + y.y + y.z + y.w;
    #pragma unroll
    for (int off = 1; off < 64; off <<= 1) s += __shfl_xor(s, off, 64);
    float mu = s * (1.f / 256.f);
    float4 dx;
    dx.x = y.x - mu; dx.y = y.y - mu; dx.z = y.z - mu; dx.w = y.w - mu;
    float sq = dx.x * dx.x + dx.y * dx.y + dx.z * dx.z + dx.w * dx.w;
    #pragma unroll
    for (int off = 1; off < 64; off <<= 1) sq += __shfl_xor(sq, off, 64);
    float rs = rsqrtf(sq * (1.f / 256.f) + 1e-5f);
    float4 g = *(const float4*)&gamma[lane * 4];
    float4 be = *(const float4*)&beta[lane * 4];
    half4v o;
    o.x = (h16)lrelu001(dx.x * rs * g.x + be.x);
    o.y = (h16)lrelu001(dx.y * rs * g.y + be.y);
    o.z = (h16)lrelu001(dx.z * rs * g.z + be.z);
    o.w = (h16)lrelu001(dx.w * rs * g.w + be.w);
    *(half4v*)&hmid[(size_t)node * D1 + lane * 4] = o;
}

// ---- gather2: wave per dst node; 4 edges in parallel (16 lanes x 8B); inline weights ----
__global__ __launch_bounds__(256) void gather2_kernel(const h16* __restrict__ h2,
                                                      const float* __restrict__ asad2,
                                                      const int* __restrict__ rowStart,
                                                      const int* __restrict__ srcIdx,
                                                      const float* __restrict__ b2,
                                                      float* __restrict__ out, int n) {
    const int lane = threadIdx.x & 63;
    const int node = (blockIdx.x * 256 + threadIdx.x) >> 6;
    if (node >= n) return;
    const int li = lane & 15, eh = lane >> 4;
    const int c0 = li * 4;
    const float ad_n = asad2[(size_t)node * 2 + 1];
    float acc[4] = {0.f, 0.f, 0.f, 0.f};
    float den = 0.f;
    if (eh == 0) {                     // self-loop
        float w0 = expf(lrelu02(asad2[(size_t)node * 2] + ad_n));
        half4v sv = *(const half4v*)&h2[(size_t)node * HID + c0];
        #pragma unroll
        for (int i = 0; i < 4; ++i) acc[i] = (float)sv[i] * w0;
        den = w0;
    }
    const int beg = rowStart[node], end = rowStart[node + 1];
    int j = beg;
    for (; j + 7 < end; j += 8) {      // 8 edges per iter (2 quads)
        int e0 = j + eh, e1 = j + 4 + eh;
        int s0 = srcIdx[e0], s1 = srcIdx[e1];
        float a0 = asad2[(size_t)s0 * 2], a1 = asad2[(size_t)s1 * 2];
        half4v r0 = *(const half4v*)&h2[(size_t)s0 * HID + c0];
        half4v r1 = *(const half4v*)&h2[(size_t)s1 * HID + c0];
        float w0 = expf(lrelu02(a0 + ad_n));
        float w1 = expf(lrelu02(a1 + ad_n));
        #pragma unroll
        for (int i = 0; i < 4; ++i) {
            acc[i] = fmaf((float)r0[i], w0, acc[i]);
            acc[i] = fmaf((float)r1[i], w1, acc[i]);
        }
        den += w0 + w1;
    }
    for (; j < end; j += 4) {          // quad tail (predicated)
        int e = j + eh;
        bool v = e < end;
        int s = v ? srcIdx[e] : 0;
        float w = v ? expf(lrelu02(asad2[(size_t)s * 2] + ad_n)) : 0.f;
        half4v r = *(const half4v*)&h2[(size_t)s * HID + c0];
        #pragma unroll
        for (int i = 0; i < 4; ++i) acc[i] = fmaf((float)r[i], w, acc[i]);
        den += w;
    }
    #pragma unroll
    for (int i = 0; i < 4; ++i) {
        acc[i] += __shfl_xor(acc[i], 32, 64);
        acc[i] += __shfl_xor(acc[i], 16, 64);
    }
    den += __shfl_xor(den, 32, 64);
    den += __shfl_xor(den, 16, 64);
    if (lane < 16) {
        float inv = 1.f / (den + 1e-16f);
        float4 bv = *(const float4*)&b2[c0];
        float4 o;
        o.x = acc[0] * inv + bv.x;
        o.y = acc[1] * inv + bv.y;
        o.z = acc[2] * inv + bv.z;
        o.w = acc[3] * inv + bv.w;
        *(float4*)&out[(size_t)node * HID + c0] = o;
    }
}

extern "C" void kernel_launch(void* const* d_in, const int* in_sizes, int n_in,
                              void* d_out, int out_size, void* d_ws, size_t ws_size,
                              hipStream_t stream) {
    const float* x      = (const float*)d_in[0];
    const int*   ei     = (const int*)d_in[1];
    const float* W1     = (const float*)d_in[2];
    const float* a_src1 = (const float*)d_in[3];
    const float* a_dst1 = (const float*)d_in[4];
    const float* b1     = (const float*)d_in[5];
    const float* gamma  = (const float*)d_in[6];
    const float* beta   = (const float*)d_in[7];
    const float* W2     = (const float*)d_in[8];
    const float* a_src2 = (const float*)d_in[9];
    const float* a_dst2 = (const float*)d_in[10];
    const float* b2     = (const float*)d_in[11];
    float* out = (float*)d_out;

    const int N = in_sizes[0] / IN_CH;
    const int E = in_sizes[1] / 2;
    const int NP = (N + 63) & ~63;          // row-pad for 64-row MFMA tiles

    // workspace layout (float slots)
    float* ws = (float*)d_ws;
    size_t off = 0;
    h16*   h1   = (h16*)(ws + off); off += (size_t)128 * N;    // [N][256] halfs
    h16*   hmid = (h16*)(ws + off); off += (size_t)128 * NP;   // [NP][256] halfs
    h16*   h2   = (h16*)(ws + off); off += (size_t)32 * N;     // [N][64] halfs
    float* asad = ws + off;         off += (size_t)8 * N;      // [N][8]
    float* asad2= ws + off;         off += (size_t)2 * N;      // [N][2]
    h16*   wE1  = (h16*)(ws + off); off += (size_t)2 * E;      // [E][4] halfs
    int* srcIdx    = (int*)(ws + off); off += E;
    int* rowStart  = (int*)(ws + off); off += N + 1;
    int* cursor    = (int*)(ws + off); off += N;
    int* blockSums = (int*)(ws + off); off += 64;
    h16* w1t = (h16*)(ws + off); off += 17408;                 // [272][128] halfs
    h16* w2t = (h16*)(ws + off); off += 10240;                 // [80][256] halfs

    const int nodeBlocks  = (N + 3) / 4;
    const int nodeBlocksP = (NP + 3) / 4;
    const int nThreadBlocksE = (E + 255) / 256;
    const int scanBlocks = (N + SCAN_BLK - 1) / SCAN_BLK;      // <= 64 for N <= 65536

    // CSR counters must be zero before hist (inside setup)
    hipMemsetAsync(cursor, 0, (size_t)N * 4, stream);
    setup_kernel<<<4 + nThreadBlocksE, 256, 0, stream>>>(
        W1, W2, a_src1, a_dst1, a_src2, a_dst2, ei, cursor, w1t, w2t, E);
    scan1_kernel<<<scanBlocks, 256, 0, stream>>>(cursor, rowStart, blockSums, N);
    scan23_kernel<<<scanBlocks, 256, 0, stream>>>(rowStart, blockSums, cursor, N, E, scanBlocks);

    // layer 1 (gemm1 before scatter so scatter can fuse edge-weight computation)
    gemm1_mfma<<<NP / 64, 256, 0, stream>>>(x, w1t, h1, asad, N);
    scatter_ewt_kernel<<<nThreadBlocksE, 256, 0, stream>>>(ei, cursor, asad, srcIdx, wE1, E);
    gather1_kernel<<<nodeBlocksP, 256, 0, stream>>>(h1, asad, wE1, rowStart, srcIdx,
                                                    b1, gamma, beta, hmid, N, NP);
    // layer 2
    gemm2_mfma<<<NP / 64, 256, 0, stream>>>(hmid, w2t, h2, asad2, N);
    gather2_kernel<<<nodeBlocks, 256, 0, stream>>>(h2, asad2, rowStart, srcIdx,
                                                   b2, out, N);
}